// Round 14
// baseline (136.948 us; speedup 1.0000x reference)
//
#include <hip/hip_runtime.h>

// Quantizer via bf16x3-split MFMA GEMM + exact-fp32 recheck of near-ties.
//   x: [16,64,32,32] fp32, embed: [64,8192] fp32
//   out[row][c] = embedT[argmax_j (f_row.e_j - ||e_j||^2/2)][c]
//
// R23: NT=8 pipe balance x R22 occupancy. Per-pipe model (finally): a wave-
// stage issues 16 ds_read_b128 (~192 cyc on the per-CU LDS pipe) regardless
// of NT; NT=4 covers 96 MFMA (116 cyc/SIMD) -> LDS-BOUND at any occupancy
// (R22's 43% plateau); NT=8 covers 192 (233 cyc) -> matrix-bound. R15's NT=8
// was grid-limited to 2 blocks/CU (512 blocks), NOT vgpr-limited. Fix: keep
// NT=8, split codes into 32 chunks x 256 (4 stages), grid 32x32=1024 ->
// 4 blocks/CU, 16 waves/CU. pb2+iq packed into u32 (b2 as ROUND-UP f16:
// only ever MORE flags -> conservative-safe) keeps workspace at 12.1MB.
// prep + reduce-structure otherwise byte-equivalent to R21.

typedef __attribute__((ext_vector_type(8))) __bf16 bf16x8;
typedef __attribute__((ext_vector_type(4))) float f32x4;
typedef unsigned int u32;
typedef unsigned short u16;
typedef unsigned long long u64;

union frag_cast { f32x4 f; bf16x8 b; };
__device__ __forceinline__ bf16x8 as_bf16x8(f32x4 v) { frag_cast u; u.f = v; return u.b; }

#define N_ROWS  16384
#define E_DIM   64
#define N_EMBED 8192
#define NCHUNK  32
#define COLS_PER_BLOCK (N_EMBED / NCHUNK)   // 256
#define N_ST (COLS_PER_BLOCK / 64)          // 4 stages of 64 codes
#define ROWS_PER_BLOCK 512                  // 4 waves x 128 pixels
#define N_ROWBLK (N_ROWS / ROWS_PER_BLOCK)  // 32
#define NT 8                                // pixel-tiles per wave
#define MARGIN_THR 2e-3f

// ---- workspace byte offsets (~12.1 MB total)
#define WS_AH   0u              // pixel hi  [16384][64] bf16 (2 MB)
#define WS_AL   (2u << 20)      // pixel lo  (2 MB)
#define WS_B    (4u << 20)      // codes: 128 groups x [hi 64x128B | lo 64x128B] (2 MB)
#define WS_ET   (6u << 20)      // embedT fp32 [8192][64] (2 MB)
#define WS_BIAS (8u << 20)      // -||e_j||^2/2 (32 KB)
#define WS_PB1  (WS_BIAS + (64u << 10))     // [32][16384] f32 best (2 MB)
#define WS_PX   (WS_PB1 + (2u << 20))       // [32][16384] u32 {f16 b2 | u16 iq} (2 MB)

union h16 { _Float16 h; u16 s; };

__device__ __forceinline__ u32 pack_b2_iq(float b2, int iq) {
    h16 u; u.h = (_Float16)b2;               // RNE
    if ((float)u.h < b2) u.s += (b2 >= 0.f) ? 1 : (u16)0xFFFF;  // round UP (toward +inf)
    return ((u32)u.s << 16) | (u32)(iq & 0xffff);
}
__device__ __forceinline__ float unpack_b2(u32 p) {
    h16 u; u.s = (u16)(p >> 16); return (float)u.h;
}

__device__ __forceinline__ u32 f32_key(float s) {
    u32 u = __float_as_uint(s);
    return (u & 0x80000000u) ? ~u : (u | 0x80000000u);
}

__device__ __forceinline__ void async16(const void* g, void* l) {
    __builtin_amdgcn_global_load_lds(
        (const __attribute__((address_space(1))) void*)g,
        (__attribute__((address_space(3))) void*)l, 16, 0, 0);
}

// ---- K1: prep. Blocks 0..255: split x -> A_hi/A_lo [row][64] bf16.
//          Blocks 256..383: embedT fp32, bias, and swizzled interleaved code groups.
__global__ __launch_bounds__(256) void prep(
        const float* __restrict__ x, const float* __restrict__ embed, char* ws) {
    __shared__ float tile[64][65];
    __bf16* Ah = (__bf16*)(ws + WS_AH);
    __bf16* Al = (__bf16*)(ws + WS_AL);
    float*  eT = (float*)(ws + WS_ET);
    float*  bias = (float*)(ws + WS_BIAS);
    const int t = threadIdx.x;
    const int blk = blockIdx.x;

    if (blk < 256) {
        const int b = blk >> 4, p0 = (blk & 15) * 64;
        {
            const int c = t >> 2, seg = (t & 3) * 16;
            const float* src = x + b * 65536 + c * 1024 + p0 + seg;
#pragma unroll
            for (int i = 0; i < 16; ++i) tile[c][seg + i] = src[i];
        }
        __syncthreads();
        const int p = t >> 2, cq = (t & 3) * 16;
        const long row = b * 1024 + p0 + p;
        bf16x8 vh0, vh1, vl0, vl1;
#pragma unroll
        for (int i = 0; i < 16; ++i) {
            float f = tile[cq + i][p];
            __bf16 h = (__bf16)f;
            __bf16 l = (__bf16)(f - (float)h);
            if (i < 8) { vh0[i] = h; vl0[i] = l; }
            else       { vh1[i - 8] = h; vl1[i - 8] = l; }
        }
        *(bf16x8*)(Ah + row * 64 + cq) = vh0;
        *(bf16x8*)(Ah + row * 64 + cq + 8) = vh1;
        *(bf16x8*)(Al + row * 64 + cq) = vl0;
        *(bf16x8*)(Al + row * 64 + cq + 8) = vl1;
    } else {
        const int g = blk - 256;             // 64-code group
        const int jbase = g * 64;
        char* Bg = ws + WS_B + (size_t)g * 16384;
        {
            const int c = t >> 2, seg = (t & 3) * 16;
            const float* src = embed + c * N_EMBED + jbase + seg;
#pragma unroll
            for (int i = 0; i < 16; ++i) tile[c][seg + i] = src[i];
        }
        __syncthreads();
        if (t < 64) {
            float s = 0.f;
#pragma unroll
            for (int c = 0; c < 64; ++c) { float v = tile[c][t]; s = fmaf(v, v, s); }
            bias[jbase + t] = -0.5f * s;
        }
        const int jl = t >> 2, cq = (t & 3) * 16;   // channels cq..cq+15
        bf16x8 vh0, vh1, vl0, vl1;
#pragma unroll
        for (int i = 0; i < 16; ++i) {
            float f = tile[cq + i][jl];
            eT[(long)(jbase + jl) * 64 + cq + i] = f;
            __bf16 h = (__bf16)f;
            __bf16 l = (__bf16)(f - (float)h);
            if (i < 8) { vh0[i] = h; vl0[i] = l; }
            else       { vh1[i - 8] = h; vl1[i - 8] = l; }
        }
        // granule-XOR swizzle: logical granule k (8 bf16) of code jl stored at
        // position k ^ (jl & 7). Keeps staging contiguous, LDS reads conflict-free.
        const int k0 = (cq >> 3), sw = jl & 7;
        __bf16* hi = (__bf16*)Bg + jl * 64;
        __bf16* lo = (__bf16*)(Bg + 8192) + jl * 64;
        *(bf16x8*)(hi + ((k0 ^ sw) * 8))       = vh0;
        *(bf16x8*)(hi + (((k0 + 1) ^ sw) * 8)) = vh1;
        *(bf16x8*)(lo + ((k0 ^ sw) * 8))       = vl0;
        *(bf16x8*)(lo + (((k0 + 1) ^ sw) * 8)) = vl1;
    }
}

// ---- K2: MFMA GEMM + running (quad-max top-2) argmax.
// grid 1024 blocks (32 rowblk x 32 chunks), 256 thr, 4 blocks/CU target
// (VGPR ~116 <= 128 bin -> 4 waves/SIMD; LDS 32KB x4 = 128KB).
__global__ __launch_bounds__(256, 2) void qdist(const char* __restrict__ ws_c, char* __restrict__ ws) {
    __shared__ __align__(16) char smem[2][16384];
    const __bf16* Ah = (const __bf16*)(ws_c + WS_AH);
    const __bf16* Al = (const __bf16*)(ws_c + WS_AL);
    const char* Bws = ws_c + WS_B;
    const float* biasg = (const float*)(ws_c + WS_BIAS);
    float* pb1 = (float*)(ws + WS_PB1);
    u32*   px  = (u32*)(ws + WS_PX);

    const int t = threadIdx.x;
    const int wv = t >> 6, lane = t & 63, ln = lane & 15, q = lane >> 4;
    const int rb = blockIdx.x >> 5, chunk = blockIdx.x & 31;
    const int row0 = rb * ROWS_PER_BLOCK;
    const int col0 = chunk * COLS_PER_BLOCK;
    const int g0 = col0 >> 6;               // first 64-code group of this chunk

    // resident pixel fragments (B-operand): 8 pixel-tiles x 2 K-halves x {hi,lo}
    f32x4 pfh[NT][2], pfl[NT][2];
#pragma unroll
    for (int nt = 0; nt < NT; ++nt) {
        long row = row0 + wv * 128 + nt * 16 + ln;
        long base = row * 64 + q * 8;
        pfh[nt][0] = *(const f32x4*)(Ah + base);
        pfh[nt][1] = *(const f32x4*)(Ah + base + 32);
        pfl[nt][0] = *(const f32x4*)(Al + base);
        pfl[nt][1] = *(const f32x4*)(Al + base + 32);
    }
    asm volatile("" :
        "+v"(pfh[0][0]), "+v"(pfh[0][1]), "+v"(pfh[1][0]), "+v"(pfh[1][1]),
        "+v"(pfh[2][0]), "+v"(pfh[2][1]), "+v"(pfh[3][0]), "+v"(pfh[3][1]),
        "+v"(pfh[4][0]), "+v"(pfh[4][1]), "+v"(pfh[5][0]), "+v"(pfh[5][1]),
        "+v"(pfh[6][0]), "+v"(pfh[6][1]), "+v"(pfh[7][0]), "+v"(pfh[7][1]));
    asm volatile("" :
        "+v"(pfl[0][0]), "+v"(pfl[0][1]), "+v"(pfl[1][0]), "+v"(pfl[1][1]),
        "+v"(pfl[2][0]), "+v"(pfl[2][1]), "+v"(pfl[3][0]), "+v"(pfl[3][1]),
        "+v"(pfl[4][0]), "+v"(pfl[4][1]), "+v"(pfl[5][0]), "+v"(pfl[5][1]),
        "+v"(pfl[6][0]), "+v"(pfl[6][1]), "+v"(pfl[7][0]), "+v"(pfl[7][1]));

    float b1[NT], b2[NT]; int iq[NT];
#pragma unroll
    for (int k = 0; k < NT; ++k) { b1[k] = -3.4e38f; b2[k] = -3.4e38f; iq[k] = 0; }

    // swizzled fragment read offsets: code cl=ct*16+ln; hi-K0 granule q^(ln&7)
    const int s7 = ln & 7;
    const int rdbase = ln * 128 + ((q ^ s7) << 4);

    auto issue = [&](int st) {
        const char* src = Bws + (size_t)(g0 + st) * 16384;
        char* dst = smem[st & 1];
#pragma unroll
        for (int s = 0; s < 4; ++s)
            async16(src + s * 4096 + wv * 1024 + lane * 16,
                    dst + s * 4096 + wv * 1024);
    };

    issue(0);
    for (int st = 0; st < N_ST; ++st) {
        __syncthreads();                 // own staging drained (vmcnt0 before barrier);
        if (st + 1 < N_ST) issue(st + 1);// all waves done reading buf[(st+1)&1]
        const char* buf = smem[st & 1];
        __builtin_amdgcn_s_setprio(1);
#pragma unroll
        for (int ct = 0; ct < 4; ++ct) {
            const int boff = ct * 2048 + rdbase;
            bf16x8 ah0 = *(const bf16x8*)(buf + boff);
            bf16x8 ah1 = *(const bf16x8*)(buf + (boff ^ 64));
            bf16x8 al0 = *(const bf16x8*)(buf + 8192 + boff);
            bf16x8 al1 = *(const bf16x8*)(buf + 8192 + (boff ^ 64));
            const int cbase = col0 + st * 64 + ct * 16;
            f32x4 bv = *(const f32x4*)(biasg + cbase + q * 4);  // bias for 4 codes
            const int jq = cbase + q * 4;
#pragma unroll
            for (int nt = 0; nt < NT; ++nt) {
                f32x4 acc = __builtin_amdgcn_mfma_f32_16x16x32_bf16(al0, as_bf16x8(pfh[nt][0]), bv, 0, 0, 0);
                acc = __builtin_amdgcn_mfma_f32_16x16x32_bf16(al1, as_bf16x8(pfh[nt][1]), acc, 0, 0, 0);
                acc = __builtin_amdgcn_mfma_f32_16x16x32_bf16(ah0, as_bf16x8(pfl[nt][0]), acc, 0, 0, 0);
                acc = __builtin_amdgcn_mfma_f32_16x16x32_bf16(ah1, as_bf16x8(pfl[nt][1]), acc, 0, 0, 0);
                acc = __builtin_amdgcn_mfma_f32_16x16x32_bf16(ah0, as_bf16x8(pfh[nt][0]), acc, 0, 0, 0);
                acc = __builtin_amdgcn_mfma_f32_16x16x32_bf16(ah1, as_bf16x8(pfh[nt][1]), acc, 0, 0, 0);
                // quad max (4 codes of one pixel)
                float mx = fmaxf(fmaxf(acc[0], acc[1]), fmaxf(acc[2], acc[3]));
                b2[nt] = fmaxf(b2[nt], fminf(b1[nt], mx));
                bool gt = mx > b1[nt];
                b1[nt] = fmaxf(b1[nt], mx);
                iq[nt] = gt ? jq : iq[nt];
            }
        }
        __builtin_amdgcn_s_setprio(0);
    }

    // merge across the 4 quads (same pixel lives in lanes ln, ln+16, ln+32, ln+48)
#pragma unroll
    for (int m = 16; m < 64; m <<= 1) {
#pragma unroll
        for (int nt = 0; nt < NT; ++nt) {
            float o1 = __shfl_xor(b1[nt], m);
            int   oi = __shfl_xor(iq[nt], m);
            float o2 = __shfl_xor(b2[nt], m);
            b2[nt] = fmaxf(fmaxf(fminf(b1[nt], o1), o2), b2[nt]);
            bool take = (o1 > b1[nt]) || (o1 == b1[nt] && oi < iq[nt]);
            if (take) { b1[nt] = o1; iq[nt] = oi; }
        }
    }
    if (q == 0) {
#pragma unroll
        for (int nt = 0; nt < NT; ++nt) {
            int pixel = row0 + wv * 128 + nt * 16 + ln;
            int o = chunk * N_ROWS + pixel;
            pb1[o] = b1[nt];
            px[o]  = pack_b2_iq(b2[nt], iq[nt]);
        }
    }
}

// ---- K3: merge chunks per row (4 lanes/row x 8 chunks) + exact quad rescore
// (x from LDS-staged slice) + inline wave-cooperative rescan for flags.
// 256 blocks x 256 thr; a block's 64 rows = 64 consecutive pixels of one image.
__global__ __launch_bounds__(256) void reduce_rows(const float* __restrict__ x, char* ws,
                                                   float* __restrict__ out) {
    __shared__ float fl[64][65];                   // [channel][pixel-in-block]
    const float* pb1 = (const float*)(ws + WS_PB1);
    const u32*   px  = (const u32*)(ws + WS_PX);
    const float* eT = (const float*)(ws + WS_ET);
    const float* bias = (const float*)(ws + WS_BIAS);
    const int t = threadIdx.x;
    const int lane = t & 63, wv = t >> 6;
    const int row = (blockIdx.x * 256 + t) >> 2;
    const int sub = t & 3;
    const int rl = (row & 1023) & 63;              // pixel-in-block

    // stage the block's x slice: 64 channels x 64 consecutive pixels, coalesced
    {
        const int b = blockIdx.x >> 4;             // image index (64 rows/blk, 1024/img)
        const int p0 = (blockIdx.x * 64) & 1023;   // first pixel of this block
        const int c = t >> 2, seg = sub * 16;
        const float* src = x + b * 65536 + c * 1024 + p0 + seg;
#pragma unroll
        for (int i = 0; i < 16; ++i) fl[c][seg + i] = src[i];
    }
    __syncthreads();

    // per-lane merge over chunks sub*8 .. sub*8+7 (coalesced across the wave)
    float m1 = -3.4e38f, m2 = -3.4e38f; int mi = 0;
#pragma unroll
    for (int k = 0; k < 8; ++k) {
        const int ch = sub * 8 + k;
        float o1 = pb1[ch * N_ROWS + row];
        u32   pk = px[ch * N_ROWS + row];
        int   oi = (int)(pk & 0xffffu);
        float o2 = unpack_b2(pk);
        m2 = fmaxf(fmaxf(fminf(m1, o1), o2), m2);
        if (o1 > m1 || (o1 == m1 && oi < mi)) { m1 = o1; mi = oi; }
    }
    // merge across the 4 lanes of this row (xor masks 1,2 stay in-group)
#pragma unroll
    for (int m = 1; m < 4; m <<= 1) {
        float o1 = __shfl_xor(m1, m);
        int   oi = __shfl_xor(mi, m);
        float o2 = __shfl_xor(m2, m);
        m2 = fmaxf(fmaxf(fminf(m1, o1), o2), m2);
        bool take = (o1 > m1) || (o1 == m1 && oi < mi);
        if (take) { m1 = o1; mi = oi; }
    }

    const bool flagged = (m1 - m2 < MARGIN_THR);   // uniform across row's 4 lanes
    if (!flagged) {
        // exact fp32 rescore of winning quad: lane sub scores code mi+sub;
        // x channels from LDS (2-way bank alias, free)
        const int j = mi + sub;
        const f32x4* ecd = (const f32x4*)(eT + (size_t)j * 64);
        float s = bias[j];
#pragma unroll
        for (int v = 0; v < 16; ++v) {
            f32x4 ev = ecd[v];
            s = fmaf(fl[v * 4 + 0][rl], ev[0], s);
            s = fmaf(fl[v * 4 + 1][rl], ev[1], s);
            s = fmaf(fl[v * 4 + 2][rl], ev[2], s);
            s = fmaf(fl[v * 4 + 3][rl], ev[3], s);
        }
        // argmax across the 4 lanes; tie -> lowest j
        float best = s; int bj = j;
#pragma unroll
        for (int m = 1; m < 4; m <<= 1) {
            float os = __shfl_xor(best, m);
            int   oj = __shfl_xor(bj, m);
            bool take = (os > best) || (os == best && oj < bj);
            if (take) { best = os; bj = oj; }
        }
        // cooperative row write: 4 lanes x 4 f32x4
        const f32x4* src = (const f32x4*)(eT + (size_t)bj * 64);
        f32x4* dst = (f32x4*)(out + (size_t)row * 64);
#pragma unroll
        for (int v = 0; v < 4; ++v) dst[v * 4 + sub] = src[v * 4 + sub];
    }

    // ---- rare path: whole wave rescans each flagged row of its 16 rows ----
    u64 bal = __ballot(flagged);
    const int wrow0 = blockIdx.x * 64 + wv * 16;     // first row of this wave
    while (bal) {
        const int b = __ffsll(bal) - 1;
        const int rw = b >> 2;
        bal &= ~(0xFull << (rw * 4));
        const int r = wrow0 + rw;
        const int rlr = wv * 16 + rw;                // pixel-in-block of row r
        const float rb1 = __shfl(m1, rw * 4);        // row's merged approx max
        const float cutoff = rb1 - 2.0f * MARGIN_THR;

        // x row from LDS (same address across lanes -> broadcast, conflict-free)
        float xr[64];
#pragma unroll
        for (int c = 0; c < 64; ++c) xr[c] = fl[c][rlr];

        u64 bestk = 0ull;
        for (int ch = 0; ch < NCHUNK; ++ch) {
            // any code that could truly win has approx >= rb1 - 2*eps, and its
            // chunk max pb1 >= that; cutoff uses 2*THR (2x slack vs the same
            // eps<=THR/2 assumption the margin test relies on).
            if (pb1[ch * N_ROWS + r] < cutoff) continue;   // wave-uniform branch
#pragma unroll
            for (int k = 0; k < 4; ++k) {
                const int j = ch * 256 + lane * 4 + k;
                const f32x4* ecd = (const f32x4*)(eT + (size_t)j * 64);
                f32x4 a0 = {0.f, 0.f, 0.f, 0.f}, a1 = a0, a2 = a0, a3 = a0;
#pragma unroll
                for (int v = 0; v < 4; ++v) {
                    f32x4 e0 = ecd[v * 4 + 0], e1 = ecd[v * 4 + 1];
                    f32x4 e2 = ecd[v * 4 + 2], e3 = ecd[v * 4 + 3];
#pragma unroll
                    for (int kk = 0; kk < 4; ++kk) {
                        a0[kk] = fmaf(xr[v * 16 + kk],      e0[kk], a0[kk]);
                        a1[kk] = fmaf(xr[v * 16 + 4 + kk],  e1[kk], a1[kk]);
                        a2[kk] = fmaf(xr[v * 16 + 8 + kk],  e2[kk], a2[kk]);
                        a3[kk] = fmaf(xr[v * 16 + 12 + kk], e3[kk], a3[kk]);
                    }
                }
                f32x4 a01 = a0 + a1, a23 = a2 + a3;
                f32x4 as = a01 + a23;
                float s = bias[j] + ((as[0] + as[1]) + (as[2] + as[3]));
                u64 key = ((u64)f32_key(s) << 32) | (u32)(~(u32)j);
                bestk = (key > bestk) ? key : bestk;
            }
        }
        // wave-wide max (all lanes end with the same key)
#pragma unroll
        for (int m = 1; m < 64; m <<= 1) {
            u64 o = __shfl_xor(bestk, m);
            bestk = (o > bestk) ? o : bestk;
        }
        const int idx = (int)(~(u32)(bestk & 0xffffffffull));
        out[(size_t)r * 64 + lane] = eT[(size_t)idx * 64 + lane];
    }
}

extern "C" void kernel_launch(void* const* d_in, const int* in_sizes, int n_in,
                              void* d_out, int out_size, void* d_ws, size_t ws_size,
                              hipStream_t stream) {
    const float* x     = (const float*)d_in[0];
    const float* embed = (const float*)d_in[1];
    float* out = (float*)d_out;
    char* ws = (char*)d_ws;

    prep<<<384, 256, 0, stream>>>(x, embed, ws);
    qdist<<<N_ROWBLK * NCHUNK, 256, 0, stream>>>(ws, ws);
    reduce_rows<<<256, 256, 0, stream>>>(x, ws, out);
}